// Round 3
// baseline (1342.650 us; speedup 1.0000x reference)
//
#include <hip/hip_runtime.h>

typedef unsigned short u16;

#define BB 16
#define CC 512
#define DD 256
#define NHW 4096

__device__ __forceinline__ float bf2f(u16 h) {
    union { unsigned u; float f; } v; v.u = ((unsigned)h) << 16; return v.f;
}
__device__ __forceinline__ u16 f2bf(float f) {
    unsigned u = __float_as_uint(f);
    u = u + 0x7fffu + ((u >> 16) & 1u);   // round-to-nearest-even
    return (u16)(u >> 16);
}
__device__ __forceinline__ float4 ld_bf4(const u16* p) {
    ushort4 q = *(const ushort4*)p;
    float4 r; r.x = bf2f(q.x); r.y = bf2f(q.y); r.z = bf2f(q.z); r.w = bf2f(q.w);
    return r;
}
__device__ __forceinline__ void st_bf4(u16* p, float4 v) {
    ushort4 q; q.x = f2bf(v.x); q.y = f2bf(v.y); q.z = f2bf(v.z); q.w = f2bf(v.w);
    *(ushort4*)p = q;
}

// ---------------- K1: theta/phi/g = W @ x, per (batch, weight). fp32 in, bf16 out ----------------
__global__ __launch_bounds__(256) void k_tpg(
    const float* __restrict__ x, const float* __restrict__ Wt,
    const float* __restrict__ Wp, const float* __restrict__ Wg,
    u16* __restrict__ theta, u16* __restrict__ phi, u16* __restrict__ g)
{
    int bz = blockIdx.z;
    int b = bz / 3, sel = bz - b * 3;
    const float* Wm = (sel == 0) ? Wt : ((sel == 1) ? Wp : Wg);
    u16* outp = ((sel == 0) ? theta : ((sel == 1) ? phi : g)) + (size_t)b * DD * NHW;
    const float* X = x + (size_t)b * CC * NHW;

    __shared__ float As[16][64];
    __shared__ float Bs[16][64];
    int t = threadIdx.x;
    int tx = t & 15, ty = t >> 4;
    int m0 = blockIdx.y * 64, n0 = blockIdx.x * 64;
    int am = t >> 2, ak = (t & 3) * 4;   // A loader: row m0+am, k = k0+ak..+3
    int bk = t >> 4, bn = (t & 15) * 4;  // B loader: row k0+bk, col n0+bn..+3

    float acc[4][4] = {};

    for (int k0 = 0; k0 < CC; k0 += 16) {
        float4 av = *(const float4*)(Wm + (size_t)(m0 + am) * CC + (k0 + ak));
        float4 bv = *(const float4*)(X + (size_t)(k0 + bk) * NHW + (n0 + bn));
        __syncthreads();
        As[ak + 0][am] = av.x; As[ak + 1][am] = av.y; As[ak + 2][am] = av.z; As[ak + 3][am] = av.w;
        *(float4*)&Bs[bk][bn] = bv;
        __syncthreads();
        #pragma unroll
        for (int kk = 0; kk < 16; kk++) {
            const float4 aa = *(const float4*)&As[kk][ty * 4];
            const float4 bb = *(const float4*)&Bs[kk][tx * 4];
            const float ar[4] = {aa.x, aa.y, aa.z, aa.w};
            const float br[4] = {bb.x, bb.y, bb.z, bb.w};
            #pragma unroll
            for (int i = 0; i < 4; i++)
                #pragma unroll
                for (int j = 0; j < 4; j++)
                    acc[i][j] = fmaf(ar[i], br[j], acc[i][j]);
        }
    }
    #pragma unroll
    for (int i = 0; i < 4; i++) {
        u16* p = outp + (size_t)(m0 + ty * 4 + i) * NHW + (n0 + tx * 4);
        st_bf4(p, make_float4(acc[i][0], acc[i][1], acc[i][2], acc[i][3]));
    }
}

// ---------------- K2: f[i,j] = sum_n theta[i,n] * max(phi[j,n], phi[j+1,n]) ----------------
__global__ __launch_bounds__(256) void k_f(
    const u16* __restrict__ theta, const u16* __restrict__ phi, float* __restrict__ f)
{
    int b = blockIdx.z;
    const u16* A = theta + (size_t)b * DD * NHW;
    const u16* P = phi + (size_t)b * DD * NHW;
    float* F = f + (size_t)b * DD * 256;

    __shared__ float As[16][64];
    __shared__ float Bs[16][64];
    int t = threadIdx.x;
    int tx = t & 15, ty = t >> 4;
    int m0 = blockIdx.y * 64, j0 = blockIdx.x * 64;
    int am = t >> 2, ak = (t & 3) * 4;
    int jj = j0 + am;
    int jn = min(jj + 1, DD - 1);

    float acc[4][4] = {};

    for (int k0 = 0; k0 < NHW; k0 += 16) {
        float4 av = ld_bf4(A + (size_t)(m0 + am) * NHW + (k0 + ak));
        float4 p0 = ld_bf4(P + (size_t)jj * NHW + (k0 + ak));
        float4 p1 = ld_bf4(P + (size_t)jn * NHW + (k0 + ak));
        float4 pm = make_float4(fmaxf(p0.x, p1.x), fmaxf(p0.y, p1.y),
                                fmaxf(p0.z, p1.z), fmaxf(p0.w, p1.w));
        __syncthreads();
        As[ak + 0][am] = av.x; As[ak + 1][am] = av.y; As[ak + 2][am] = av.z; As[ak + 3][am] = av.w;
        Bs[ak + 0][am] = pm.x; Bs[ak + 1][am] = pm.y; Bs[ak + 2][am] = pm.z; Bs[ak + 3][am] = pm.w;
        __syncthreads();
        #pragma unroll
        for (int kk = 0; kk < 16; kk++) {
            const float4 aa = *(const float4*)&As[kk][ty * 4];
            const float4 bb = *(const float4*)&Bs[kk][tx * 4];
            const float ar[4] = {aa.x, aa.y, aa.z, aa.w};
            const float br[4] = {bb.x, bb.y, bb.z, bb.w};
            #pragma unroll
            for (int i = 0; i < 4; i++)
                #pragma unroll
                for (int j = 0; j < 4; j++)
                    acc[i][j] = fmaf(ar[i], br[j], acc[i][j]);
        }
    }
    #pragma unroll
    for (int i = 0; i < 4; i++) {
        int row = m0 + ty * 4 + i;
        #pragma unroll
        for (int j = 0; j < 4; j++) {
            int col = j0 + tx * 4 + j;
            if (col < DD - 1) F[(size_t)row * 256 + col] = acc[i][j];
        }
    }
}

// ---------------- K3: row softmax over 255 valid cols; col 255 zeroed ----------------
__global__ __launch_bounds__(256) void k_softmax(float* __restrict__ f)
{
    int row = blockIdx.x;  // B*256 rows
    float* p = f + (size_t)row * 256;
    int t = threadIdx.x;
    int wid = t >> 6, lane = t & 63;
    __shared__ float sm[4], ss[4];

    float v = (t < DD - 1) ? p[t] : -3.4e38f;
    float m = v;
    #pragma unroll
    for (int o = 32; o > 0; o >>= 1) m = fmaxf(m, __shfl_xor(m, o, 64));
    if (lane == 0) sm[wid] = m;
    __syncthreads();
    m = fmaxf(fmaxf(sm[0], sm[1]), fmaxf(sm[2], sm[3]));

    float e = (t < DD - 1) ? expf(v - m) : 0.f;
    float s = e;
    #pragma unroll
    for (int o = 32; o > 0; o >>= 1) s += __shfl_xor(s, o, 64);
    if (lane == 0) ss[wid] = s;
    __syncthreads();
    s = ss[0] + ss[1] + ss[2] + ss[3];

    p[t] = e / s;  // t==255 -> 0, enabling K=256 in k_y
}

// ---------------- K4: y[i,n] = sum_j f[i,j] * max(g[j,n], g[j+1,n]) ----------------
__global__ __launch_bounds__(256) void k_y(
    const float* __restrict__ f, const u16* __restrict__ g, u16* __restrict__ y)
{
    int b = blockIdx.z;
    const float* A = f + (size_t)b * DD * 256;
    const u16* G = g + (size_t)b * DD * NHW;
    u16* Y = y + (size_t)b * DD * NHW;

    __shared__ float As[16][64];
    __shared__ float Bs[16][64];
    int t = threadIdx.x;
    int tx = t & 15, ty = t >> 4;
    int m0 = blockIdx.y * 64, n0 = blockIdx.x * 64;
    int am = t >> 2, ak = (t & 3) * 4;
    int bk = t >> 4, bn = (t & 15) * 4;

    float acc[4][4] = {};

    for (int k0 = 0; k0 < DD; k0 += 16) {
        float4 av = *(const float4*)(A + (size_t)(m0 + am) * 256 + (k0 + ak));
        int r = k0 + bk, r1 = min(r + 1, DD - 1);
        float4 g0 = ld_bf4(G + (size_t)r * NHW + (n0 + bn));
        float4 g1 = ld_bf4(G + (size_t)r1 * NHW + (n0 + bn));
        float4 bv = make_float4(fmaxf(g0.x, g1.x), fmaxf(g0.y, g1.y),
                                fmaxf(g0.z, g1.z), fmaxf(g0.w, g1.w));
        __syncthreads();
        As[ak + 0][am] = av.x; As[ak + 1][am] = av.y; As[ak + 2][am] = av.z; As[ak + 3][am] = av.w;
        *(float4*)&Bs[bk][bn] = bv;
        __syncthreads();
        #pragma unroll
        for (int kk = 0; kk < 16; kk++) {
            const float4 aa = *(const float4*)&As[kk][ty * 4];
            const float4 bb = *(const float4*)&Bs[kk][tx * 4];
            const float ar[4] = {aa.x, aa.y, aa.z, aa.w};
            const float br[4] = {bb.x, bb.y, bb.z, bb.w};
            #pragma unroll
            for (int i = 0; i < 4; i++)
                #pragma unroll
                for (int j = 0; j < 4; j++)
                    acc[i][j] = fmaf(ar[i], br[j], acc[i][j]);
        }
    }
    #pragma unroll
    for (int i = 0; i < 4; i++) {
        u16* p = Y + (size_t)(m0 + ty * 4 + i) * NHW + (n0 + tx * 4);
        st_bf4(p, make_float4(acc[i][0], acc[i][1], acc[i][2], acc[i][3]));
    }
}

// ---------------- K5: out = W_final @ y + x (fp32 W/x, bf16 y, FP32 out) ----------------
__global__ __launch_bounds__(256) void k_z(
    const float* __restrict__ Wf, const u16* __restrict__ y,
    const float* __restrict__ x, float* __restrict__ out)
{
    int b = blockIdx.z;
    const u16* Y = y + (size_t)b * DD * NHW;
    const float* X = x + (size_t)b * CC * NHW;
    float* O = out + (size_t)b * CC * NHW;

    __shared__ float As[16][64];
    __shared__ float Bs[16][64];
    int t = threadIdx.x;
    int tx = t & 15, ty = t >> 4;
    int m0 = blockIdx.y * 64, n0 = blockIdx.x * 64;
    int am = t >> 2, ak = (t & 3) * 4;
    int bk = t >> 4, bn = (t & 15) * 4;

    float acc[4][4] = {};

    for (int k0 = 0; k0 < DD; k0 += 16) {
        float4 av = *(const float4*)(Wf + (size_t)(m0 + am) * DD + (k0 + ak));
        float4 bv = ld_bf4(Y + (size_t)(k0 + bk) * NHW + (n0 + bn));
        __syncthreads();
        As[ak + 0][am] = av.x; As[ak + 1][am] = av.y; As[ak + 2][am] = av.z; As[ak + 3][am] = av.w;
        *(float4*)&Bs[bk][bn] = bv;
        __syncthreads();
        #pragma unroll
        for (int kk = 0; kk < 16; kk++) {
            const float4 aa = *(const float4*)&As[kk][ty * 4];
            const float4 bb = *(const float4*)&Bs[kk][tx * 4];
            const float ar[4] = {aa.x, aa.y, aa.z, aa.w};
            const float br[4] = {bb.x, bb.y, bb.z, bb.w};
            #pragma unroll
            for (int i = 0; i < 4; i++)
                #pragma unroll
                for (int j = 0; j < 4; j++)
                    acc[i][j] = fmaf(ar[i], br[j], acc[i][j]);
        }
    }
    #pragma unroll
    for (int i = 0; i < 4; i++) {
        int row = m0 + ty * 4 + i;
        float4 xr = *(const float4*)(X + (size_t)row * NHW + (n0 + tx * 4));
        *(float4*)(O + (size_t)row * NHW + (n0 + tx * 4)) =
            make_float4(acc[i][0] + xr.x, acc[i][1] + xr.y,
                        acc[i][2] + xr.z, acc[i][3] + xr.w);
    }
}

extern "C" void kernel_launch(void* const* d_in, const int* in_sizes, int n_in,
                              void* d_out, int out_size, void* d_ws, size_t ws_size,
                              hipStream_t stream)
{
    const float* x  = (const float*)d_in[0];
    const float* Wt = (const float*)d_in[1];
    const float* Wp = (const float*)d_in[2];
    const float* Wg = (const float*)d_in[3];
    const float* Wf = (const float*)d_in[4];
    float* out = (float*)d_out;

    // Workspace layout (bf16 intermediates): theta | phi | g | f(fp32)
    // 3 * 16*256*4096 * 2B = 100.7 MB  +  16*256*256 * 4B = 4.2 MB
    u16* theta = (u16*)d_ws;
    u16* phi   = theta + (size_t)BB * DD * NHW;
    u16* g     = phi   + (size_t)BB * DD * NHW;
    float* f   = (float*)(g + (size_t)BB * DD * NHW);
    u16* y     = theta;  // theta dead after k_f; reuse for y

    dim3 blk(256);
    k_tpg<<<dim3(NHW / 64, DD / 64, BB * 3), blk, 0, stream>>>(x, Wt, Wp, Wg, theta, phi, g);
    k_f<<<dim3(4, 4, BB), blk, 0, stream>>>(theta, phi, f);
    k_softmax<<<dim3(BB * DD), blk, 0, stream>>>(f);
    k_y<<<dim3(NHW / 64, DD / 64, BB), blk, 0, stream>>>(f, g, y);
    k_z<<<dim3(NHW / 64, CC / 64, BB), blk, 0, stream>>>(Wf, y, x, out);
}

// Round 5
// 513.386 us; speedup vs baseline: 2.6153x; 2.6153x over previous
//
#include <hip/hip_runtime.h>

typedef unsigned short u16;
typedef __attribute__((ext_vector_type(4))) float f32x4;
typedef __attribute__((ext_vector_type(8))) short bf16x8;

#define BB 16
#define CC 512
#define DD 256
#define NHW 4096

__device__ __forceinline__ float bf2f(u16 h) {
    union { unsigned u; float f; } v; v.u = ((unsigned)h) << 16; return v.f;
}
__device__ __forceinline__ u16 f2bf(float f) {
    unsigned u = __float_as_uint(f);
    u = u + 0x7fffu + ((u >> 16) & 1u);   // RNE
    return (u16)(u >> 16);
}
__device__ __forceinline__ float4 ld_bf4(const u16* p) {
    ushort4 q = *(const ushort4*)p;
    float4 r; r.x = bf2f(q.x); r.y = bf2f(q.y); r.z = bf2f(q.z); r.w = bf2f(q.w);
    return r;
}
__device__ __forceinline__ void st_bf4(u16* p, float4 v) {
    ushort4 q; q.x = f2bf(v.x); q.y = f2bf(v.y); q.z = f2bf(v.z); q.w = f2bf(v.w);
    *(ushort4*)p = q;
}
__device__ __forceinline__ unsigned bfmax2(unsigned a, unsigned b) {
    float al = __uint_as_float(a << 16), ah = __uint_as_float(a & 0xffff0000u);
    float bl = __uint_as_float(b << 16), bh = __uint_as_float(b & 0xffff0000u);
    float ml = fmaxf(al, bl), mh = fmaxf(ah, bh);
    return (__float_as_uint(ml) >> 16) | (__float_as_uint(mh) & 0xffff0000u);
}
__device__ __forceinline__ u16 bfmax1(u16 a, u16 b) {
    return bf2f(a) > bf2f(b) ? a : b;
}
__device__ __forceinline__ void gll16(const void* g, void* l) {
    __builtin_amdgcn_global_load_lds(
        (const __attribute__((address_space(1))) void*)g,
        (__attribute__((address_space(3))) void*)l, 16, 0, 0);
}
__device__ __forceinline__ f32x4 mfma16(bf16x8 a, bf16x8 b, f32x4 c) {
    return __builtin_amdgcn_mfma_f32_16x16x32_bf16(a, b, c, 0, 0, 0);
}
// shared compute: A,B LDS tiles are [128 rows][32 k] bf16
__device__ __forceinline__ void mfma_tile(const u16* As, const u16* Bs,
                                          int wy, int wx, int lane, f32x4 acc[4][4]) {
    bf16x8 af[4], bf[4];
    int q = lane >> 4, r = lane & 15;
    #pragma unroll
    for (int i = 0; i < 4; i++)
        af[i] = *(const bf16x8*)&As[(wy * 64 + i * 16 + r) * 32 + q * 8];
    #pragma unroll
    for (int j = 0; j < 4; j++)
        bf[j] = *(const bf16x8*)&Bs[(wx * 64 + j * 16 + r) * 32 + q * 8];
    #pragma unroll
    for (int i = 0; i < 4; i++)
        #pragma unroll
        for (int j = 0; j < 4; j++)
            acc[i][j] = mfma16(af[i], bf[j], acc[i][j]);
}

// ============================= MFMA PATH =============================

// convert the four weight matrices to bf16: Wb=[3][256][512], Wfb=[512][256]
__global__ __launch_bounds__(256) void mk_wcvt(
    const float* __restrict__ Wt, const float* __restrict__ Wp,
    const float* __restrict__ Wg, const float* __restrict__ Wf,
    u16* __restrict__ Wb, u16* __restrict__ Wfb)
{
    int gid = blockIdx.x * 256 + threadIdx.x;   // 0..131071
    int sel = gid >> 15;
    int off = (gid & 32767) * 4;
    const float* S = sel == 0 ? Wt : sel == 1 ? Wp : sel == 2 ? Wg : Wf;
    u16* D = sel < 3 ? (Wb + (size_t)sel * 131072) : Wfb;
    float4 v = *(const float4*)&S[off];
    st_bf4(&D[off], v);
}

// transpose+cast x[b][c][n] (fp32) -> xbT[b][n][c] (bf16)
__global__ __launch_bounds__(256) void mk_prep(
    const float* __restrict__ x, u16* __restrict__ xbT)
{
    int b = blockIdx.z, c0 = blockIdx.y * 64, n0 = blockIdx.x * 64;
    const float* X = x + ((size_t)b * CC + c0) * NHW + n0;
    u16* O = xbT + ((size_t)b * NHW + n0) * CC + c0;
    __shared__ u16 Ts[64][72];
    int t = threadIdx.x;
    #pragma unroll
    for (int rep = 0; rep < 4; rep++) {
        int idx = rep * 256 + t;
        int r = idx >> 4, c4 = (idx & 15) * 4;     // r: c-dim, c4: n-dim
        float4 v = *(const float4*)&X[(size_t)r * NHW + c4];
        Ts[r][c4 + 0] = f2bf(v.x); Ts[r][c4 + 1] = f2bf(v.y);
        Ts[r][c4 + 2] = f2bf(v.z); Ts[r][c4 + 3] = f2bf(v.w);
    }
    __syncthreads();
    // write-out: 64 n-rows x 8 c-groups = 512 work items -> exactly 2 reps
    #pragma unroll
    for (int rep = 0; rep < 2; rep++) {
        int idx = rep * 256 + t;
        int nn = idx >> 3, cc = (idx & 7) * 8;
        ushort4 a, b2;
        a.x  = Ts[cc + 0][nn]; a.y  = Ts[cc + 1][nn];
        a.z  = Ts[cc + 2][nn]; a.w  = Ts[cc + 3][nn];
        b2.x = Ts[cc + 4][nn]; b2.y = Ts[cc + 5][nn];
        b2.z = Ts[cc + 6][nn]; b2.w = Ts[cc + 7][nn];
        *(ushort4*)&O[(size_t)nn * CC + cc] = a;
        *(ushort4*)&O[(size_t)nn * CC + cc + 4] = b2;
    }
}

// theta/phi natural [D][N]; g transposed gT[N][D]
__global__ __launch_bounds__(256) void mk_tpg(
    const u16* __restrict__ Wb, const u16* __restrict__ xbT,
    u16* __restrict__ theta, u16* __restrict__ phi, u16* __restrict__ gT)
{
    int bz = blockIdx.z;
    int b = bz / 3, sel = bz - b * 3;
    const u16* A = Wb + (size_t)sel * DD * CC;
    const u16* B = xbT + (size_t)b * NHW * CC;
    int m0 = blockIdx.y * 128, n0 = blockIdx.x * 128;
    __shared__ u16 As[128 * 32], Bs[128 * 32];
    int t = threadIdx.x, w = t >> 6, lane = t & 63;
    int wy = w >> 1, wx = w & 1;
    f32x4 acc[4][4] = {};

    for (int k0 = 0; k0 < CC; k0 += 32) {
        #pragma unroll
        for (int rr = 0; rr < 2; rr++) {
            int idx = rr * 256 + t, row = idx >> 2, c8 = (idx & 3) * 8;
            gll16(A + (size_t)(m0 + row) * CC + k0 + c8, &As[idx * 8]);
            gll16(B + (size_t)(n0 + row) * CC + k0 + c8, &Bs[idx * 8]);
        }
        __syncthreads();
        mfma_tile(As, Bs, wy, wx, lane, acc);
        __syncthreads();
    }

    int q = lane >> 4, r = lane & 15;
    if (sel < 2) {
        u16* O = (sel == 0 ? theta : phi) + (size_t)b * DD * NHW;
        #pragma unroll
        for (int i = 0; i < 4; i++) {
            int m = m0 + wy * 64 + i * 16 + q * 4;
            #pragma unroll
            for (int j = 0; j < 4; j++) {
                int n = n0 + wx * 64 + j * 16 + r;
                #pragma unroll
                for (int rg = 0; rg < 4; rg++)
                    O[(size_t)(m + rg) * NHW + n] = f2bf(acc[i][j][rg]);
            }
        }
    } else {
        u16* O = gT + (size_t)b * NHW * DD;
        #pragma unroll
        for (int j = 0; j < 4; j++) {
            int n = n0 + wx * 64 + j * 16 + r;
            #pragma unroll
            for (int i = 0; i < 4; i++) {
                int m = m0 + wy * 64 + i * 16 + q * 4;
                ushort4 v;
                v.x = f2bf(acc[i][j][0]); v.y = f2bf(acc[i][j][1]);
                v.z = f2bf(acc[i][j][2]); v.w = f2bf(acc[i][j][3]);
                *(ushort4*)&O[(size_t)n * DD + m] = v;
            }
        }
    }
}

// f_part[s][b*256+i][j] fp32, split-K over N=4096 (4 splits)
__global__ __launch_bounds__(256) void mk_f(
    const u16* __restrict__ theta, const u16* __restrict__ phi,
    float* __restrict__ f_part)
{
    int bz = blockIdx.z;            // b*4+s
    int b = bz >> 2, s = bz & 3;
    const u16* A = theta + (size_t)b * DD * NHW;
    const u16* P = phi + (size_t)b * DD * NHW;
    int m0 = blockIdx.y * 128, n0 = blockIdx.x * 128;
    __shared__ u16 As[128 * 32], Bs[128 * 32];
    int t = threadIdx.x, w = t >> 6, lane = t & 63;
    int wy = w >> 1, wx = w & 1;
    f32x4 acc[4][4] = {};

    for (int kt = 0; kt < 32; kt++) {
        int k0 = s * 1024 + kt * 32;
        #pragma unroll
        for (int rr = 0; rr < 2; rr++) {
            int idx = rr * 256 + t, row = idx >> 2, c8 = (idx & 3) * 8;
            gll16(A + (size_t)(m0 + row) * NHW + k0 + c8, &As[idx * 8]);
            int jj = n0 + row, jn = min(jj + 1, DD - 1);
            uint4 p0 = *(const uint4*)&P[(size_t)jj * NHW + k0 + c8];
            uint4 p1 = *(const uint4*)&P[(size_t)jn * NHW + k0 + c8];
            uint4 o;
            o.x = bfmax2(p0.x, p1.x); o.y = bfmax2(p0.y, p1.y);
            o.z = bfmax2(p0.z, p1.z); o.w = bfmax2(p0.w, p1.w);
            *(uint4*)&Bs[idx * 8] = o;
        }
        __syncthreads();
        mfma_tile(As, Bs, wy, wx, lane, acc);
        __syncthreads();
    }

    int q = lane >> 4, r = lane & 15;
    float* F = f_part + ((size_t)s * BB + b) * DD * 256;
    #pragma unroll
    for (int i = 0; i < 4; i++) {
        int m = m0 + wy * 64 + i * 16 + q * 4;
        #pragma unroll
        for (int j = 0; j < 4; j++) {
            int n = n0 + wx * 64 + j * 16 + r;
            #pragma unroll
            for (int rg = 0; rg < 4; rg++)
                F[(size_t)(m + rg) * 256 + n] = acc[i][j][rg];
        }
    }
}

// sum 4 partials, softmax over 255, col255=0, emit bf16 f
__global__ __launch_bounds__(256) void mk_softmax(
    const float* __restrict__ f_part, u16* __restrict__ f)
{
    int row = blockIdx.x;           // b*256+i, 4096 rows
    int t = threadIdx.x;
    int wid = t >> 6, lane = t & 63;
    __shared__ float sm[4], ss[4];

    float v = 0.f;
    #pragma unroll
    for (int s = 0; s < 4; s++)
        v += f_part[((size_t)s * BB * DD + row) * 256 + t];

    float vv = (t < DD - 1) ? v : -3.4e38f;
    float m = vv;
    #pragma unroll
    for (int o = 32; o > 0; o >>= 1) m = fmaxf(m, __shfl_xor(m, o, 64));
    if (lane == 0) sm[wid] = m;
    __syncthreads();
    m = fmaxf(fmaxf(sm[0], sm[1]), fmaxf(sm[2], sm[3]));

    float e = (t < DD - 1) ? expf(vv - m) : 0.f;
    float sum = e;
    #pragma unroll
    for (int o = 32; o > 0; o >>= 1) sum += __shfl_xor(sum, o, 64);
    if (lane == 0) ss[wid] = sum;
    __syncthreads();
    sum = ss[0] + ss[1] + ss[2] + ss[3];

    f[(size_t)row * 256 + t] = (t < DD - 1) ? f2bf(e / sum) : (u16)0;
}

// y = f * pool(g): A=f[256][256] bf16, B from gT (pool along contiguous j), out yT[N][D]
__global__ __launch_bounds__(256) void mk_y(
    const u16* __restrict__ f, const u16* __restrict__ gT, u16* __restrict__ yT)
{
    int b = blockIdx.z;
    const u16* A = f + (size_t)b * DD * 256;
    const u16* G = gT + (size_t)b * NHW * DD;
    int m0 = blockIdx.y * 128, n0 = blockIdx.x * 128;
    __shared__ u16 As[128 * 32], Bs[128 * 32];
    int t = threadIdx.x, w = t >> 6, lane = t & 63;
    int wy = w >> 1, wx = w & 1;
    f32x4 acc[4][4] = {};

    for (int k0 = 0; k0 < 256; k0 += 32) {
        #pragma unroll
        for (int rr = 0; rr < 2; rr++) {
            int idx = rr * 256 + t, row = idx >> 2, c8 = (idx & 3) * 8;
            gll16(A + (size_t)(m0 + row) * 256 + k0 + c8, &As[idx * 8]);
            const u16* src = &G[(size_t)(n0 + row) * DD + k0 + c8];
            ushort4 v0 = *(const ushort4*)src;
            ushort4 v1 = *(const ushort4*)(src + 4);
            u16 extra = src[8];   // may read into next row / pad: multiplied by f[:,255]=0
            u16 o[8];
            o[0] = bfmax1(v0.x, v0.y); o[1] = bfmax1(v0.y, v0.z);
            o[2] = bfmax1(v0.z, v0.w); o[3] = bfmax1(v0.w, v1.x);
            o[4] = bfmax1(v1.x, v1.y); o[5] = bfmax1(v1.y, v1.z);
            o[6] = bfmax1(v1.z, v1.w); o[7] = bfmax1(v1.w, extra);
            ushort4 a = {o[0], o[1], o[2], o[3]}, b4 = {o[4], o[5], o[6], o[7]};
            *(ushort4*)&Bs[idx * 8] = a;
            *(ushort4*)&Bs[idx * 8 + 4] = b4;
        }
        __syncthreads();
        mfma_tile(As, Bs, wy, wx, lane, acc);
        __syncthreads();
    }

    int q = lane >> 4, r = lane & 15;
    u16* O = yT + (size_t)b * NHW * DD;
    #pragma unroll
    for (int j = 0; j < 4; j++) {
        int n = n0 + wx * 64 + j * 16 + r;
        #pragma unroll
        for (int i = 0; i < 4; i++) {
            int m = m0 + wy * 64 + i * 16 + q * 4;
            ushort4 v;
            v.x = f2bf(acc[i][j][0]); v.y = f2bf(acc[i][j][1]);
            v.z = f2bf(acc[i][j][2]); v.w = f2bf(acc[i][j][3]);
            *(ushort4*)&O[(size_t)n * DD + m] = v;
        }
    }
}

// z = Wf @ y + x: A=Wfb[512][256], B=yT, fp32 out
__global__ __launch_bounds__(256) void mk_z(
    const u16* __restrict__ Wfb, const u16* __restrict__ yT,
    const float* __restrict__ x, float* __restrict__ out)
{
    int b = blockIdx.z;
    const u16* B = yT + (size_t)b * NHW * DD;
    const float* X = x + (size_t)b * CC * NHW;
    float* O = out + (size_t)b * CC * NHW;
    int m0 = blockIdx.y * 128, n0 = blockIdx.x * 128;
    __shared__ u16 As[128 * 32], Bs[128 * 32];
    int t = threadIdx.x, w = t >> 6, lane = t & 63;
    int wy = w >> 1, wx = w & 1;
    f32x4 acc[4][4] = {};

    for (int k0 = 0; k0 < 256; k0 += 32) {
        #pragma unroll
        for (int rr = 0; rr < 2; rr++) {
            int idx = rr * 256 + t, row = idx >> 2, c8 = (idx & 3) * 8;
            gll16(Wfb + (size_t)(m0 + row) * DD + k0 + c8, &As[idx * 8]);
            gll16(B + (size_t)(n0 + row) * DD + k0 + c8, &Bs[idx * 8]);
        }
        __syncthreads();
        mfma_tile(As, Bs, wy, wx, lane, acc);
        __syncthreads();
    }

    int q = lane >> 4, r = lane & 15;
    #pragma unroll
    for (int i = 0; i < 4; i++) {
        int m = m0 + wy * 64 + i * 16 + q * 4;
        #pragma unroll
        for (int j = 0; j < 4; j++) {
            int n = n0 + wx * 64 + j * 16 + r;
            #pragma unroll
            for (int rg = 0; rg < 4; rg++)
                O[(size_t)(m + rg) * NHW + n] = acc[i][j][rg] + X[(size_t)(m + rg) * NHW + n];
        }
    }
}

// ============================= LEGACY PATH (r3, proven) =============================

__global__ __launch_bounds__(256) void k_tpg(
    const float* __restrict__ x, const float* __restrict__ Wt,
    const float* __restrict__ Wp, const float* __restrict__ Wg,
    u16* __restrict__ theta, u16* __restrict__ phi, u16* __restrict__ g)
{
    int bz = blockIdx.z;
    int b = bz / 3, sel = bz - b * 3;
    const float* Wm = (sel == 0) ? Wt : ((sel == 1) ? Wp : Wg);
    u16* outp = ((sel == 0) ? theta : ((sel == 1) ? phi : g)) + (size_t)b * DD * NHW;
    const float* X = x + (size_t)b * CC * NHW;

    __shared__ float As[16][64];
    __shared__ float Bs[16][64];
    int t = threadIdx.x;
    int tx = t & 15, ty = t >> 4;
    int m0 = blockIdx.y * 64, n0 = blockIdx.x * 64;
    int am = t >> 2, ak = (t & 3) * 4;
    int bk = t >> 4, bn = (t & 15) * 4;

    float acc[4][4] = {};

    for (int k0 = 0; k0 < CC; k0 += 16) {
        float4 av = *(const float4*)(Wm + (size_t)(m0 + am) * CC + (k0 + ak));
        float4 bv = *(const float4*)(X + (size_t)(k0 + bk) * NHW + (n0 + bn));
        __syncthreads();
        As[ak + 0][am] = av.x; As[ak + 1][am] = av.y; As[ak + 2][am] = av.z; As[ak + 3][am] = av.w;
        *(float4*)&Bs[bk][bn] = bv;
        __syncthreads();
        #pragma unroll
        for (int kk = 0; kk < 16; kk++) {
            const float4 aa = *(const float4*)&As[kk][ty * 4];
            const float4 bb = *(const float4*)&Bs[kk][tx * 4];
            const float ar[4] = {aa.x, aa.y, aa.z, aa.w};
            const float br[4] = {bb.x, bb.y, bb.z, bb.w};
            #pragma unroll
            for (int i = 0; i < 4; i++)
                #pragma unroll
                for (int j = 0; j < 4; j++)
                    acc[i][j] = fmaf(ar[i], br[j], acc[i][j]);
        }
    }
    #pragma unroll
    for (int i = 0; i < 4; i++) {
        u16* p = outp + (size_t)(m0 + ty * 4 + i) * NHW + (n0 + tx * 4);
        st_bf4(p, make_float4(acc[i][0], acc[i][1], acc[i][2], acc[i][3]));
    }
}

__global__ __launch_bounds__(256) void k_f(
    const u16* __restrict__ theta, const u16* __restrict__ phi, float* __restrict__ f)
{
    int b = blockIdx.z;
    const u16* A = theta + (size_t)b * DD * NHW;
    const u16* P = phi + (size_t)b * DD * NHW;
    float* F = f + (size_t)b * DD * 256;

    __shared__ float As[16][64];
    __shared__ float Bs[16][64];
    int t = threadIdx.x;
    int tx = t & 15, ty = t >> 4;
    int m0 = blockIdx.y * 64, j0 = blockIdx.x * 64;
    int am = t >> 2, ak = (t & 3) * 4;
    int jj = j0 + am;
    int jn = min(jj + 1, DD - 1);

    float acc[4][4] = {};

    for (int k0 = 0; k0 < NHW; k0 += 16) {
        float4 av = ld_bf4(A + (size_t)(m0 + am) * NHW + (k0 + ak));
        float4 p0 = ld_bf4(P + (size_t)jj * NHW + (k0 + ak));
        float4 p1 = ld_bf4(P + (size_t)jn * NHW + (k0 + ak));
        float4 pm = make_float4(fmaxf(p0.x, p1.x), fmaxf(p0.y, p1.y),
                                fmaxf(p0.z, p1.z), fmaxf(p0.w, p1.w));
        __syncthreads();
        As[ak + 0][am] = av.x; As[ak + 1][am] = av.y; As[ak + 2][am] = av.z; As[ak + 3][am] = av.w;
        Bs[ak + 0][am] = pm.x; Bs[ak + 1][am] = pm.y; Bs[ak + 2][am] = pm.z; Bs[ak + 3][am] = pm.w;
        __syncthreads();
        #pragma unroll
        for (int kk = 0; kk < 16; kk++) {
            const float4 aa = *(const float4*)&As[kk][ty * 4];
            const float4 bb = *(const float4*)&Bs[kk][tx * 4];
            const float ar[4] = {aa.x, aa.y, aa.z, aa.w};
            const float br[4] = {bb.x, bb.y, bb.z, bb.w};
            #pragma unroll
            for (int i = 0; i < 4; i++)
                #pragma unroll
                for (int j = 0; j < 4; j++)
                    acc[i][j] = fmaf(ar[i], br[j], acc[i][j]);
        }
    }
    #pragma unroll
    for (int i = 0; i < 4; i++) {
        int row = m0 + ty * 4 + i;
        #pragma unroll
        for (int j = 0; j < 4; j++) {
            int col = j0 + tx * 4 + j;
            if (col < DD - 1) F[(size_t)row * 256 + col] = acc[i][j];
        }
    }
}

__global__ __launch_bounds__(256) void k_softmax(float* __restrict__ f)
{
    int row = blockIdx.x;
    float* p = f + (size_t)row * 256;
    int t = threadIdx.x;
    int wid = t >> 6, lane = t & 63;
    __shared__ float sm[4], ss[4];

    float v = (t < DD - 1) ? p[t] : -3.4e38f;
    float m = v;
    #pragma unroll
    for (int o = 32; o > 0; o >>= 1) m = fmaxf(m, __shfl_xor(m, o, 64));
    if (lane == 0) sm[wid] = m;
    __syncthreads();
    m = fmaxf(fmaxf(sm[0], sm[1]), fmaxf(sm[2], sm[3]));

    float e = (t < DD - 1) ? expf(v - m) : 0.f;
    float s = e;
    #pragma unroll
    for (int o = 32; o > 0; o >>= 1) s += __shfl_xor(s, o, 64);
    if (lane == 0) ss[wid] = s;
    __syncthreads();
    s = ss[0] + ss[1] + ss[2] + ss[3];

    p[t] = e / s;
}

__global__ __launch_bounds__(256) void k_y(
    const float* __restrict__ f, const u16* __restrict__ g, u16* __restrict__ y)
{
    int b = blockIdx.z;
    const float* A = f + (size_t)b * DD * 256;
    const u16* G = g + (size_t)b * DD * NHW;
    u16* Y = y + (size_t)b * DD * NHW;

    __shared__ float As[16][64];
    __shared__ float Bs[16][64];
    int t = threadIdx.x;
    int tx = t & 15, ty = t >> 4;
    int m0 = blockIdx.y * 64, n0 = blockIdx.x * 64;
    int am = t >> 2, ak = (t & 3) * 4;
    int bk = t >> 4, bn = (t & 15) * 4;

    float acc[4][4] = {};

    for (int k0 = 0; k0 < DD; k0 += 16) {
        float4 av = *(const float4*)(A + (size_t)(m0 + am) * 256 + (k0 + ak));
        int rr = k0 + bk, r1 = min(rr + 1, DD - 1);
        float4 g0 = ld_bf4(G + (size_t)rr * NHW + (n0 + bn));
        float4 g1 = ld_bf4(G + (size_t)r1 * NHW + (n0 + bn));
        float4 bv = make_float4(fmaxf(g0.x, g1.x), fmaxf(g0.y, g1.y),
                                fmaxf(g0.z, g1.z), fmaxf(g0.w, g1.w));
        __syncthreads();
        As[ak + 0][am] = av.x; As[ak + 1][am] = av.y; As[ak + 2][am] = av.z; As[ak + 3][am] = av.w;
        *(float4*)&Bs[bk][bn] = bv;
        __syncthreads();
        #pragma unroll
        for (int kk = 0; kk < 16; kk++) {
            const float4 aa = *(const float4*)&As[kk][ty * 4];
            const float4 bb = *(const float4*)&Bs[kk][tx * 4];
            const float ar[4] = {aa.x, aa.y, aa.z, aa.w};
            const float br[4] = {bb.x, bb.y, bb.z, bb.w};
            #pragma unroll
            for (int i = 0; i < 4; i++)
                #pragma unroll
                for (int j = 0; j < 4; j++)
                    acc[i][j] = fmaf(ar[i], br[j], acc[i][j]);
        }
    }
    #pragma unroll
    for (int i = 0; i < 4; i++) {
        u16* p = Y + (size_t)(m0 + ty * 4 + i) * NHW + (n0 + tx * 4);
        st_bf4(p, make_float4(acc[i][0], acc[i][1], acc[i][2], acc[i][3]));
    }
}

__global__ __launch_bounds__(256) void k_z(
    const float* __restrict__ Wf, const u16* __restrict__ y,
    const float* __restrict__ x, float* __restrict__ out)
{
    int b = blockIdx.z;
    const u16* Y = y + (size_t)b * DD * NHW;
    const float* X = x + (size_t)b * CC * NHW;
    float* O = out + (size_t)b * CC * NHW;

    __shared__ float As[16][64];
    __shared__ float Bs[16][64];
    int t = threadIdx.x;
    int tx = t & 15, ty = t >> 4;
    int m0 = blockIdx.y * 64, n0 = blockIdx.x * 64;
    int am = t >> 2, ak = (t & 3) * 4;
    int bk = t >> 4, bn = (t & 15) * 4;

    float acc[4][4] = {};

    for (int k0 = 0; k0 < DD; k0 += 16) {
        float4 av = *(const float4*)(Wf + (size_t)(m0 + am) * DD + (k0 + ak));
        float4 bv = ld_bf4(Y + (size_t)(k0 + bk) * NHW + (n0 + bn));
        __syncthreads();
        As[ak + 0][am] = av.x; As[ak + 1][am] = av.y; As[ak + 2][am] = av.z; As[ak + 3][am] = av.w;
        *(float4*)&Bs[bk][bn] = bv;
        __syncthreads();
        #pragma unroll
        for (int kk = 0; kk < 16; kk++) {
            const float4 aa = *(const float4*)&As[kk][ty * 4];
            const float4 bb = *(const float4*)&Bs[kk][tx * 4];
            const float ar[4] = {aa.x, aa.y, aa.z, aa.w};
            const float br[4] = {bb.x, bb.y, bb.z, bb.w};
            #pragma unroll
            for (int i = 0; i < 4; i++)
                #pragma unroll
                for (int j = 0; j < 4; j++)
                    acc[i][j] = fmaf(ar[i], br[j], acc[i][j]);
        }
    }
    #pragma unroll
    for (int i = 0; i < 4; i++) {
        int row = m0 + ty * 4 + i;
        float4 xr = *(const float4*)(X + (size_t)row * NHW + (n0 + tx * 4));
        *(float4*)(O + (size_t)row * NHW + (n0 + tx * 4)) =
            make_float4(acc[i][0] + xr.x, acc[i][1] + xr.y,
                        acc[i][2] + xr.z, acc[i][3] + xr.w);
    }
}

extern "C" void kernel_launch(void* const* d_in, const int* in_sizes, int n_in,
                              void* d_out, int out_size, void* d_ws, size_t ws_size,
                              hipStream_t stream)
{
    const float* x  = (const float*)d_in[0];
    const float* Wt = (const float*)d_in[1];
    const float* Wp = (const float*)d_in[2];
    const float* Wg = (const float*)d_in[3];
    const float* Wf = (const float*)d_in[4];
    float* out = (float*)d_out;
    char* ws = (char*)d_ws;
    dim3 blk(256);

    // MFMA-path workspace layout
    const size_t XBT_OFF   = 0;                         // 67,108,864 B (dead after mk_tpg)
    const size_t FPART_OFF = 0;                         // 16,777,216 B (in dead xbT)
    const size_t FBF_OFF   = 16777216;                  //  2,097,152 B
    const size_t YT_OFF    = 18874368;                  // 33,554,432 B
    const size_t WB_OFF    = 67108864;                  //    786,432 B
    const size_t WFB_OFF   = 67895296;                  //    262,144 B
    const size_t TH_OFF    = 68157440;                  // 33,554,432 B
    const size_t PH_OFF    = 101711872;                 // 33,554,432 B
    const size_t GT_OFF    = 135266304;                 // 33,554,432 B
    const size_t FULL_NEED = 168820736 + 4096;          // + pad for mk_y overread

    if (ws_size >= FULL_NEED) {
        u16*   xbT    = (u16*)(ws + XBT_OFF);
        float* f_part = (float*)(ws + FPART_OFF);
        u16*   fbf    = (u16*)(ws + FBF_OFF);
        u16*   yT     = (u16*)(ws + YT_OFF);
        u16*   Wb     = (u16*)(ws + WB_OFF);
        u16*   Wfb    = (u16*)(ws + WFB_OFF);
        u16*   theta  = (u16*)(ws + TH_OFF);
        u16*   phi    = (u16*)(ws + PH_OFF);
        u16*   gT     = (u16*)(ws + GT_OFF);

        mk_wcvt<<<dim3(512), blk, 0, stream>>>(Wt, Wp, Wg, Wf, Wb, Wfb);
        mk_prep<<<dim3(64, 8, BB), blk, 0, stream>>>(x, xbT);
        mk_tpg<<<dim3(32, 2, BB * 3), blk, 0, stream>>>(Wb, xbT, theta, phi, gT);
        mk_f<<<dim3(2, 2, BB * 4), blk, 0, stream>>>(theta, phi, f_part);
        mk_softmax<<<dim3(BB * DD), blk, 0, stream>>>(f_part, fbf);
        mk_y<<<dim3(32, 2, BB), blk, 0, stream>>>(fbf, gT, yT);
        mk_z<<<dim3(32, 4, BB), blk, 0, stream>>>(Wfb, yT, x, out);
    } else {
        // legacy fp32 path (r3)
        u16* theta = (u16*)ws;
        u16* phi   = theta + (size_t)BB * DD * NHW;
        u16* g     = phi   + (size_t)BB * DD * NHW;
        float* f   = (float*)(g + (size_t)BB * DD * NHW);
        u16* y     = theta;

        k_tpg<<<dim3(NHW / 64, DD / 64, BB * 3), blk, 0, stream>>>(x, Wt, Wp, Wg, theta, phi, g);
        k_f<<<dim3(4, 4, BB), blk, 0, stream>>>(theta, phi, f);
        k_softmax<<<dim3(BB * DD), blk, 0, stream>>>(f);
        k_y<<<dim3(NHW / 64, DD / 64, BB), blk, 0, stream>>>(f, g, y);
        k_z<<<dim3(NHW / 64, CC / 64, BB), blk, 0, stream>>>(Wf, y, x, out);
    }
}